// Round 11
// baseline (1049.132 us; speedup 1.0000x reference)
//
#include <hip/hip_runtime.h>
#include <hip/hip_bf16.h>
#include <math.h>

#define N_BATCH 8
#define WDIM 64
#define TDIM 8192
#define KBINS 2048
#define NROWS (N_BATCH * TDIM)          // 65536
#define XSIZE (N_BATCH * WDIM * TDIM)   // 4194304
#define XL_OFF 0
#define XD_OFF NROWS
#define SCAL_OFF (NROWS + XSIZE)

#define MT 64                           // rows per block (vq)
#define XST 72                          // bf16 LDS x row stride
#define TAU 0.05f                       // >=16x worst-case split-bf16 vs np noise
#define MAXFLAG 8192

// ws layout (bytes):
//   0      : double wsd[4]
//   64     : float  k2[KBINS]
//   8320   : int    flag_cnt
//   8384   : int    flags[MAXFLAG]         (32 KB)
//   41216  : u64    slots[MAXFLAG]         (64 KB)
//   106752 : short  kfrag[KBINS*128]       (512 KB fragment-ordered codebook)
//   631040 : int    done[MAXFLAG]          (32 KB)
#define WS_K2_OFF   64
#define WS_CNT_OFF  8320
#define WS_FLAG_OFF 8384
#define WS_SLOT_OFF 41216
#define WS_KF_OFF   106752
#define WS_DONE_OFF 631040

typedef __attribute__((ext_vector_type(8))) short bf16x8;
typedef __attribute__((ext_vector_type(4))) float f32x4;
typedef unsigned long long u64;

static __device__ __forceinline__ short f2bf(float v) {
  __hip_bfloat16 b = __float2bfloat16(v);
  return *reinterpret_cast<short*>(&b);
}
static __device__ __forceinline__ float bf2f(short s) {
  unsigned int u = ((unsigned int)(unsigned short)s) << 16;
  return __uint_as_float(u);
}

#define GLOAD_LDS(gsrc, ldst)                                            \
  __builtin_amdgcn_global_load_lds(                                      \
      (const __attribute__((address_space(1))) unsigned int*)(gsrc),     \
      (__attribute__((address_space(3))) unsigned int*)(ldst), 16, 0, 0)

// prep: 1 block per 16-code tile. np-bit-exact k2 + fragment-ordered split-bf16
// codebook. Also inits wsd/cnt/slots/done.
__global__ void prep_kernel(const float* __restrict__ kg, float* __restrict__ k2,
                            short* __restrict__ kfrag,
                            double* __restrict__ wsd, int* __restrict__ cnt,
                            u64* __restrict__ slots, int* __restrict__ done) {
  __shared__ float skc[16 * 65];
  const int tid  = threadIdx.x;
  const int tile = blockIdx.x;           // 0..127
  const int c0   = tile * 16;
  if (tile == 0) {
    if (tid < 4) wsd[tid] = 0.0;
    if (tid == 4) *cnt = 0;
  }
  {
    int gid = tile * 256 + tid;
    if (gid < MAXFLAG) { slots[gid] = ~0ULL; done[gid] = 0; }
  }
  {
    const float4* g4 = (const float4*)(kg + (size_t)c0 * WDIM);
    int code = tid >> 4, w = (tid & 15) * 4;
    *(float4*)&skc[code * 65 + w] = g4[tid];
  }
  __syncthreads();
  if (tid < 16) {   // np-bit-exact k2 (8-accumulator pairwise)
    const float* kr = &skc[tid * 65];
    float r[8];
#pragma unroll
    for (int l = 0; l < 8; ++l) r[l] = __fmul_rn(kr[l], kr[l]);
    for (int i = 8; i < WDIM; i += 8) {
#pragma unroll
      for (int l = 0; l < 8; ++l)
        r[l] = __fadd_rn(r[l], __fmul_rn(kr[i + l], kr[i + l]));
    }
    k2[c0 + tid] = __fadd_rn(__fadd_rn(__fadd_rn(r[0], r[1]), __fadd_rn(r[2], r[3])),
                             __fadd_rn(__fadd_rn(r[4], r[5]), __fadd_rn(r[6], r[7])));
  }
  {
    const int sub  = tid >> 6;
    const int lane = tid & 63;
    const int lcol = lane & 15;
    const int quad = lane >> 4;
    const float* src = &skc[lcol * 65 + (sub & 1) * 32 + quad * 8];
    const bool lo = (sub >= 2);
    short tmp[8];
#pragma unroll
    for (int i = 0; i < 8; ++i) {
      float v = src[i];
      short h = f2bf(v);
      tmp[i] = lo ? f2bf(v - bf2f(h)) : h;
    }
    char* dst = (char*)kfrag + (size_t)tile * 4096 + sub * 1024 + lane * 16;
    *(bf16x8*)dst = *(const bf16x8*)tmp;
  }
}

// main: split-bf16 MFMA scan. 256 thr = 4 waves x 16 rows; 4 blocks/CU ->
// 16 waves/CU. Async global_load_lds double-buffer, literal buffer indices,
// ds_read-before-prefetch ordering.
__launch_bounds__(256, 4)
__global__ void vq_mfma(const float* __restrict__ x,
                        const float* __restrict__ kg,
                        const float* __restrict__ k2g,
                        const short* __restrict__ kfrag,
                        float* __restrict__ out,
                        double* __restrict__ wsd,
                        int* __restrict__ flag_cnt,
                        int* __restrict__ flags) {
  __shared__ __align__(16) char smem[36352];
  short* sxh  = (short*)smem;              // [64][72] bf16 hi   (9216 B)
  short* sxl  = (short*)(smem + 9216);     // [64][72] bf16 lo   (9216 B)
  char*  kbuf = smem + 18432;              // 2 x 8192 B chunk buffers
  float* sx2  = (float*)(smem + 34816);    // per-row x2         (256 B)
  float* sPair= (float*)(smem + 35072);    // x2 partials        (1024 B)
  int*   sIdx = (int*)  (smem + 36096);    // chosen code/row    (256 B)
  float* kd   = (float*)smem;              // epilogue [64][68] f32 (17408 B, reuses sxh/sxl)

  const int tid  = threadIdx.x;
  const int row0 = blockIdx.x * MT;
  const int n    = row0 >> 13;
  const int t0   = row0 & (TDIM - 1);

  // ---- stage x tile -> split bf16; fp32 partials ----
  const int r  = tid & 63;
  const int wq = tid >> 6;                 // w-class 0..3
  float x2p = 0.f, sxp = 0.f;
  const float* xb = x + (size_t)n * WDIM * TDIM + t0 + r;
#pragma unroll 8
  for (int i = 0; i < 16; ++i) {
    int w = 4 * i + wq;
    float v = xb[(size_t)w * TDIM];
    x2p = fmaf(v, v, x2p);
    sxp += v;
    short h = f2bf(v);
    sxh[r * XST + w] = h;
    sxl[r * XST + w] = f2bf(v - bf2f(h));
  }
  sPair[tid] = x2p;
  __syncthreads();
  if (tid < MT)
    sx2[tid] = (sPair[tid] + sPair[tid + 64]) + (sPair[tid + 128] + sPair[tid + 192]);

  // ---- A fragments: wave w owns rows w*16 + lcol ----
  const int wave = tid >> 6;
  const int lane = tid & 63;
  const int lcol = lane & 15;
  const int quad = lane >> 4;
  const int rA = wave * 16 + lcol;
  bf16x8 ah0 = *(const bf16x8*)&sxh[rA * XST + 0  + quad * 8];
  bf16x8 ah1 = *(const bf16x8*)&sxh[rA * XST + 32 + quad * 8];
  bf16x8 al0 = *(const bf16x8*)&sxl[rA * XST + 0  + quad * 8];
  bf16x8 al1 = *(const bf16x8*)&sxl[rA * XST + 32 + quad * 8];

  float bd[4], b2[4];
  int   bi[4];
#pragma unroll
  for (int i = 0; i < 4; ++i) { bd[i] = 3.0e38f; b2[i] = 3.0e38f; bi[i] = 0; }

  const char* kfg = (const char*)kfrag;

  // async prefetch of 8 KB chunk C into buffer B (each wave stages 2 KB)
#define VQ_ISSUE(C, B)                                                       \
  {                                                                          \
    const char* s = kfg + (size_t)(C) * 8192 + wave * 2048 + (lane << 4);    \
    char* d = kbuf + (B) * 8192 + wave * 2048;                               \
    GLOAD_LDS(s, d);                                                         \
    GLOAD_LDS(s + 1024, d + 1024);                                           \
  }

#define VQ_STEP(BH0, BH1, BL0, BL1, KK, CB)                                  \
  {                                                                          \
    f32x4 acc = {0.f, 0.f, 0.f, 0.f};                                        \
    acc = __builtin_amdgcn_mfma_f32_16x16x32_bf16(ah0, BH0, acc, 0, 0, 0);   \
    acc = __builtin_amdgcn_mfma_f32_16x16x32_bf16(ah1, BH1, acc, 0, 0, 0);   \
    acc = __builtin_amdgcn_mfma_f32_16x16x32_bf16(ah0, BL0, acc, 0, 0, 0);   \
    acc = __builtin_amdgcn_mfma_f32_16x16x32_bf16(ah1, BL1, acc, 0, 0, 0);   \
    acc = __builtin_amdgcn_mfma_f32_16x16x32_bf16(al0, BH0, acc, 0, 0, 0);   \
    acc = __builtin_amdgcn_mfma_f32_16x16x32_bf16(al1, BH1, acc, 0, 0, 0);   \
    const int code = (CB) + lcol;                                            \
    _Pragma("unroll")                                                        \
    for (int i = 0; i < 4; ++i) {                                            \
      float d0 = fmaf(-2.f, acc[i], KK);                                     \
      float nb2 = fminf(b2[i], fmaxf(bd[i], d0));                            \
      bool lt = d0 < bd[i];                                                  \
      bd[i] = lt ? d0 : bd[i];                                               \
      bi[i] = lt ? code : bi[i];                                             \
      b2[i] = nb2;                                                           \
    }                                                                        \
  }

  // one iteration: read chunk from buf, prefetch next into other buf, compute
#define VQ_ITER(CC, BUF)                                                     \
  {                                                                          \
    const char* tb0 = kbuf + (BUF) * 8192;                                   \
    const char* tb1 = tb0 + 4096;                                            \
    bf16x8 bh0 = *(const bf16x8*)(tb0 + 0    + (lane << 4));                 \
    bf16x8 bh1 = *(const bf16x8*)(tb0 + 1024 + (lane << 4));                 \
    bf16x8 bl0 = *(const bf16x8*)(tb0 + 2048 + (lane << 4));                 \
    bf16x8 bl1 = *(const bf16x8*)(tb0 + 3072 + (lane << 4));                 \
    bf16x8 ch0 = *(const bf16x8*)(tb1 + 0    + (lane << 4));                 \
    bf16x8 ch1 = *(const bf16x8*)(tb1 + 1024 + (lane << 4));                 \
    bf16x8 cl0 = *(const bf16x8*)(tb1 + 2048 + (lane << 4));                 \
    bf16x8 cl1 = *(const bf16x8*)(tb1 + 3072 + (lane << 4));                 \
    float k2c0 = k2g[(CC) * 32 + lcol];                                      \
    float k2c1 = k2g[(CC) * 32 + 16 + lcol];                                 \
    VQ_ISSUE(((CC) + 1) & 63, (BUF) ^ 1)                                     \
    VQ_STEP(bh0, bh1, bl0, bl1, k2c0, (CC) * 32)                             \
    VQ_STEP(ch0, ch1, cl0, cl1, k2c1, (CC) * 32 + 16)                        \
    __syncthreads();                                                         \
  }

  VQ_ISSUE(0, 0)
  __syncthreads();   // covers sxh/sxl reads + buf0 arrival
  for (int cc = 0; cc < 64; cc += 2) {
    VQ_ITER(cc, 0)
    VQ_ITER(cc + 1, 1)
  }
#undef VQ_ITER
#undef VQ_STEP
#undef VQ_ISSUE

  // ---- reduce across the 16 col-classes ----
#pragma unroll
  for (int m = 1; m < 16; m <<= 1) {
#pragma unroll
    for (int i = 0; i < 4; ++i) {
      float od  = __shfl_xor(bd[i], m, 64);
      float od2 = __shfl_xor(b2[i], m, 64);
      int   oi  = __shfl_xor(bi[i], m, 64);
      float nb2 = fminf(fminf(b2[i], od2), fmaxf(bd[i], od));
      bool take = (od < bd[i]) || (od == bd[i] && oi < bi[i]);
      bd[i] = take ? od : bd[i];
      bi[i] = take ? oi : bi[i];
      b2[i] = nb2;
    }
  }

  float fit_p = 0.f;
  if (lcol == 0) {
#pragma unroll
    for (int i = 0; i < 4; ++i) {
      int rloc = wave * 16 + quad * 4 + i;
      int rowg = row0 + rloc;
      out[XL_OFF + rowg] = (float)bi[i];
      sIdx[rloc] = bi[i];
      fit_p += bd[i] + sx2[rloc];
      if (b2[i] - bd[i] < TAU) {
        int slot = atomicAdd(flag_cnt, 1);
        if (slot < MAXFLAG) flags[slot] = rowg;
      }
    }
  }
  __syncthreads();

  // ---- gather chosen code rows (fp32) into LDS ----
  {
    int rr = tid >> 2, qt = tid & 3;
    const float4* kr4 = (const float4*)(kg + (size_t)sIdx[rr] * WDIM + qt * 16);
    float4* dst = (float4*)&kd[rr * 68 + qt * 16];
#pragma unroll
    for (int j = 0; j < 4; ++j) dst[j] = kr4[j];
  }
  __syncthreads();

  // ---- x_d transposed write + commit ----
  float commit_p = 0.f;
  float* xdb = out + XD_OFF + (size_t)n * WDIM * TDIM + t0 + r;
#pragma unroll 8
  for (int i = 0; i < 16; ++i) {
    int w = 4 * i + wq;
    float xvv = xb[(size_t)w * TDIM];
    float kvv = kd[r * 68 + w];
    float df = kvv - xvv;
    commit_p = fmaf(df, df, commit_p);
    xdb[(size_t)w * TDIM] = kvv;
  }

  float v0 = sxp, v1 = x2p, v2 = commit_p, v3 = fit_p;
#pragma unroll
  for (int off = 32; off > 0; off >>= 1) {
    v0 += __shfl_down(v0, off, 64);
    v1 += __shfl_down(v1, off, 64);
    v2 += __shfl_down(v2, off, 64);
    v3 += __shfl_down(v3, off, 64);
  }
  if (lane == 0) {
    atomicAdd(&wsd[0], (double)v0);
    atomicAdd(&wsd[1], (double)v1);
    atomicAdd(&wsd[2], (double)v2);
    atomicAdd(&wsd[3], (double)v3);
  }
}

// recheck: persistent grid; item = (flagged row, 256-code segment). The block
// finishing a row's 8th segment writes x_l + x_d. Block 0 also finalizes scalars.
__launch_bounds__(256, 4)
__global__ void recheck_scan(const float* __restrict__ x,
                             const float* __restrict__ kg,
                             const float* __restrict__ k2g,
                             const int* __restrict__ flag_cnt,
                             const int* __restrict__ flags,
                             u64* __restrict__ slots,
                             int* __restrict__ done,
                             const double* __restrict__ wsd,
                             float* __restrict__ out) {
  __shared__ float sx[WDIM];
  __shared__ float sx2s;
  __shared__ int   sLast;
  const int tid = threadIdx.x;

  if (blockIdx.x == 0 && tid == 0) {   // finalize scalars (wsd complete)
    double size = (double)XSIZE;
    double commit = wsd[2] / size;
    double fit = wsd[3] / (double)NROWS;
    double mean = wsd[0] / size;
    double var = wsd[1] / size - mean * mean;
    if (var < 0.0) var = 0.0;
    out[SCAL_OFF + 0] = (float)commit;
    out[SCAL_OFF + 1] = (float)fit;
    out[SCAL_OFF + 2] = (float)sqrt(var);
  }

  int nf = *flag_cnt;
  if (nf > MAXFLAG) nf = MAXFLAG;
  const int total = nf * 8;

  for (int g = blockIdx.x; g < total; g += 2048) {
    const int fi  = g >> 3;
    const int seg = g & 7;
    const int row = flags[fi];
    const int n = row >> 13;
    const int t = row & (TDIM - 1);
    if (tid < WDIM) sx[tid] = x[(size_t)n * WDIM * TDIM + (size_t)tid * TDIM + t];
    __syncthreads();
    if (tid == 0) {   // np-pairwise x2
      float r8[8];
#pragma unroll
      for (int l = 0; l < 8; ++l) r8[l] = __fmul_rn(sx[l], sx[l]);
      for (int i = 8; i < WDIM; i += 8) {
#pragma unroll
        for (int l = 0; l < 8; ++l)
          r8[l] = __fadd_rn(r8[l], __fmul_rn(sx[i + l], sx[i + l]));
      }
      sx2s = __fadd_rn(__fadd_rn(__fadd_rn(r8[0], r8[1]), __fadd_rn(r8[2], r8[3])),
                       __fadd_rn(__fadd_rn(r8[4], r8[5]), __fadd_rn(r8[6], r8[7])));
    }
    __syncthreads();

    const int j = seg * 256 + tid;
    const float* kr = kg + (size_t)j * WDIM;
    float c = 0.f;
#pragma unroll
    for (int w = 0; w < WDIM; ++w)
      c = __fmaf_rn(sx[w], kr[w], c);
    float d = __fadd_rn(__fsub_rn(sx2s, __fmul_rn(2.0f, c)), k2g[j]);

    u64 key = ((u64)__float_as_uint(d) << 32) | (unsigned int)j;
#pragma unroll
    for (int off = 32; off > 0; off >>= 1) {
      u64 o = __shfl_down((unsigned long long)key, off, 64);
      if (o < key) key = o;
    }
    if ((tid & 63) == 0) atomicMin(&slots[fi], key);
    __syncthreads();

    if (tid == 0) {
      __threadfence();
      int old = atomicAdd(&done[fi], 1);
      sLast = (old == 7);
    }
    __syncthreads();
    if (sLast) {
      __threadfence();
      const int bj = (int)(slots[fi] & 0xFFFFFFFFULL);
      if (tid == 0) out[XL_OFF + row] = (float)bj;
      if (tid < WDIM)
        out[XD_OFF + (size_t)n * WDIM * TDIM + (size_t)tid * TDIM + t] =
            kg[(size_t)bj * WDIM + tid];
    }
    __syncthreads();
  }
}

extern "C" void kernel_launch(void* const* d_in, const int* in_sizes, int n_in,
                              void* d_out, int out_size, void* d_ws, size_t ws_size,
                              hipStream_t stream) {
  const float* x = (const float*)d_in[0];
  const float* kg = (const float*)d_in[1];
  float* out = (float*)d_out;
  double* wsd = (double*)d_ws;
  float* k2   = (float*)((char*)d_ws + WS_K2_OFF);
  int* cnt    = (int*)((char*)d_ws + WS_CNT_OFF);
  int* flags  = (int*)((char*)d_ws + WS_FLAG_OFF);
  u64* slots  = (u64*)((char*)d_ws + WS_SLOT_OFF);
  short* kfrag= (short*)((char*)d_ws + WS_KF_OFF);
  int* done   = (int*)((char*)d_ws + WS_DONE_OFF);

  hipLaunchKernelGGL(prep_kernel, dim3(KBINS / 16), dim3(256), 0, stream,
                     kg, k2, kfrag, wsd, cnt, slots, done);
  hipLaunchKernelGGL(vq_mfma, dim3(NROWS / MT), dim3(256), 0, stream,
                     x, kg, k2, kfrag, out, wsd, cnt, flags);
  hipLaunchKernelGGL(recheck_scan, dim3(2048), dim3(256), 0, stream,
                     x, kg, k2, cnt, flags, slots, done, wsd, out);
}

// Round 12
// 235.247 us; speedup vs baseline: 4.4597x; 4.4597x over previous
//
#include <hip/hip_runtime.h>
#include <hip/hip_bf16.h>
#include <math.h>

#define N_BATCH 8
#define WDIM 64
#define TDIM 8192
#define KBINS 2048
#define NROWS (N_BATCH * TDIM)          // 65536
#define XSIZE (N_BATCH * WDIM * TDIM)   // 4194304
#define XL_OFF 0
#define XD_OFF NROWS
#define SCAL_OFF (NROWS + XSIZE)

#define MT 64                           // rows per block (vq), 128 thr, 2 waves x 2 subtiles
#define XST 72                          // bf16 LDS x row stride
#define TAU 0.05f                       // >=16x split-bf16 vs np noise
#define MAXFLAG 8192
#define NBLK (NROWS / MT)               // 1024

// ws layout (bytes):
//   0      : float k2[KBINS]            (8192)
//   8192   : int   flag_cnt             (pad to 64)
//   8256   : int   flags[MAXFLAG]       (32768)
//   41024  : u64   slots[MAXFLAG]       (65536)
//   106560 : float part[4][NBLK]        (16384)
//   122944 : char  kfrag[128 tiles * 4096]  (524288; per 16-code tile:
//            {hi k0-31 | hi k32-63 | lo k0-31 | lo k32-63} x 64 lanes x 16B)
#define WS_K2_OFF   0
#define WS_CNT_OFF  8192
#define WS_FLAG_OFF 8256
#define WS_SLOT_OFF 41024
#define WS_PART_OFF 106560
#define WS_KF_OFF   122944

typedef __attribute__((ext_vector_type(8))) short bf16x8;
typedef __attribute__((ext_vector_type(4))) float f32x4;
typedef unsigned long long u64;

static __device__ __forceinline__ short f2bf(float v) {
  __hip_bfloat16 b = __float2bfloat16(v);
  return *reinterpret_cast<short*>(&b);
}
static __device__ __forceinline__ float bf2f(short s) {
  unsigned int u = ((unsigned int)(unsigned short)s) << 16;
  return __uint_as_float(u);
}

#define GLOAD_LDS(gsrc, ldst)                                            \
  __builtin_amdgcn_global_load_lds(                                      \
      (const __attribute__((address_space(1))) unsigned int*)(gsrc),     \
      (__attribute__((address_space(3))) unsigned int*)(ldst), 16, 0, 0)

// s_waitcnt immediates (gfx9 encoding): vmcnt[3:0] | expcnt<<4 | lgkmcnt<<8
#define WAIT_VM4 0x0F74
#define WAIT_VM0 0x0F70

// prep: 1 block per 16-code tile. np-bit-exact k2 + fragment-ordered split-bf16
// codebook + ws init (cnt, slots).
__global__ void prep_kernel(const float* __restrict__ kg, float* __restrict__ k2,
                            char* __restrict__ kfrag,
                            int* __restrict__ cnt, u64* __restrict__ slots) {
  __shared__ float skc[16 * 65];
  const int tid  = threadIdx.x;
  const int tile = blockIdx.x;           // 0..127
  const int c0   = tile * 16;
  if (tile == 0 && tid == 0) *cnt = 0;
  if (tid < 64) slots[tile * 64 + tid] = ~0ULL;
  {
    const float4* g4 = (const float4*)(kg + (size_t)c0 * WDIM);
    int code = tid >> 4, w = (tid & 15) * 4;
    *(float4*)&skc[code * 65 + w] = g4[tid];
  }
  __syncthreads();
  if (tid < 16) {   // np-bit-exact k2 (8-accumulator pairwise)
    const float* kr = &skc[tid * 65];
    float r[8];
#pragma unroll
    for (int l = 0; l < 8; ++l) r[l] = __fmul_rn(kr[l], kr[l]);
    for (int i = 8; i < WDIM; i += 8) {
#pragma unroll
      for (int l = 0; l < 8; ++l)
        r[l] = __fadd_rn(r[l], __fmul_rn(kr[i + l], kr[i + l]));
    }
    k2[c0 + tid] = __fadd_rn(__fadd_rn(__fadd_rn(r[0], r[1]), __fadd_rn(r[2], r[3])),
                             __fadd_rn(__fadd_rn(r[4], r[5]), __fadd_rn(r[6], r[7])));
  }
  {
    const int sub  = tid >> 6;           // 0..3
    const int lane = tid & 63;
    const int lcol = lane & 15;
    const int quad = lane >> 4;
    const float* src = &skc[lcol * 65 + (sub & 1) * 32 + quad * 8];
    const bool lo = (sub >= 2);
    short tmp[8];
#pragma unroll
    for (int i = 0; i < 8; ++i) {
      float v = src[i];
      short h = f2bf(v);
      tmp[i] = lo ? f2bf(v - bf2f(h)) : h;
    }
    char* dst = kfrag + (size_t)tile * 4096 + sub * 1024 + lane * 16;
    *(bf16x8*)dst = *(const bf16x8*)tmp;
  }
}

// main: split-bf16 MFMA scan. 128 thr = 2 waves x 2 subtiles (32 rows/wave).
// Wave-private 3-buffer LDS ring filled by async global_load_lds, consumed
// behind explicit s_waitcnt vmcnt literals. NO barriers in the sweep.
// NO contended atomics: scalars -> per-block partial arrays; flags -> LDS
// list + one global atomicAdd per block.
__launch_bounds__(128, 2)
__global__ void vq_mfma(const float* __restrict__ x,
                        const float* __restrict__ kg,
                        const float* __restrict__ k2g,
                        const char* __restrict__ kfrag,
                        float* __restrict__ out,
                        float* __restrict__ part,
                        int* __restrict__ flag_cnt,
                        int* __restrict__ flags) {
  __shared__ __align__(16) char smem[52608];
  short* sxh   = (short*)smem;             // [64][72] bf16 hi       (9216)
  short* sxl   = (short*)(smem + 9216);    // [64][72] bf16 lo       (9216)
  float* k2f   = (float*)(smem + 18432);   // k2[2048]               (8192)
  char*  kbuf  = smem + 26624;             // 2 waves x 3 x 4096     (24576)
  float* sx2   = (float*)(smem + 51200);   // per-row x2             (256)
  float* sPair = (float*)(smem + 51456);   // partials / wave sums   (512)
  int*   sIdx  = (int*)  (smem + 51968);   // chosen code/row        (256)
  int*   sFlagCnt  = (int*)(smem + 52224);
  int*   sFlagBase = (int*)(smem + 52228);
  int*   sFlagList = (int*)(smem + 52232); // 64 ints
  float* kd    = (float*)smem;             // epilogue [64][68] f32 (reuses sxh/sxl)

  const int tid  = threadIdx.x;
  const int blk  = blockIdx.x;
  const int row0 = blk * MT;
  const int n    = row0 >> 13;
  const int t0   = row0 & (TDIM - 1);

  if (tid == 0) *sFlagCnt = 0;

  // ---- stage x tile -> split bf16; k2 -> LDS; fp32 partials ----
  const int r  = tid & 63;
  const int wh = tid >> 6;
  float x2p = 0.f, sxp = 0.f;
  const float* xb = x + (size_t)n * WDIM * TDIM + t0 + r;
#pragma unroll 8
  for (int i = 0; i < 32; ++i) {
    int w = 2 * i + wh;
    float v = xb[(size_t)w * TDIM];
    x2p = fmaf(v, v, x2p);
    sxp += v;
    short h = f2bf(v);
    sxh[r * XST + w] = h;
    sxl[r * XST + w] = f2bf(v - bf2f(h));
  }
  {
    const float4* k24 = (const float4*)k2g;
#pragma unroll
    for (int i = 0; i < 4; ++i) {
      int j = tid + i * 128;
      *(float4*)&k2f[j * 4] = k24[j];
    }
  }
  sPair[tid] = x2p;
  __syncthreads();
  if (tid < MT) sx2[tid] = sPair[tid] + sPair[tid + 64];
  __syncthreads();

  // ---- A fragments ----
  const int wave = tid >> 6;
  const int lane = tid & 63;
  const int lcol = lane & 15;
  const int quad = lane >> 4;
  const int rA0 = wave * 32 + lcol;
  const int rA1 = wave * 32 + 16 + lcol;
  bf16x8 a0h0 = *(const bf16x8*)&sxh[rA0 * XST + 0  + quad * 8];
  bf16x8 a0h1 = *(const bf16x8*)&sxh[rA0 * XST + 32 + quad * 8];
  bf16x8 a0l0 = *(const bf16x8*)&sxl[rA0 * XST + 0  + quad * 8];
  bf16x8 a0l1 = *(const bf16x8*)&sxl[rA0 * XST + 32 + quad * 8];
  bf16x8 a1h0 = *(const bf16x8*)&sxh[rA1 * XST + 0  + quad * 8];
  bf16x8 a1h1 = *(const bf16x8*)&sxh[rA1 * XST + 32 + quad * 8];
  bf16x8 a1l0 = *(const bf16x8*)&sxl[rA1 * XST + 0  + quad * 8];
  bf16x8 a1l1 = *(const bf16x8*)&sxl[rA1 * XST + 32 + quad * 8];

  float bd[8], b2[8];
  int   bi[8];
#pragma unroll
  for (int i = 0; i < 8; ++i) { bd[i] = 3.0e38f; b2[i] = 3.0e38f; bi[i] = 0; }

  char* mybuf = kbuf + wave * 12288;     // 3 x 4096 private ring
  const char* kfg = kfrag;

  // issue async stage of tile C into ring slot B (4 x 1KB glds)
#define VQ_ISSUE(C, B)                                                       \
  if ((C) < 128) {                                                           \
    const char* s = kfg + (size_t)(C) * 4096 + (lane << 4);                  \
    char* d = mybuf + (B) * 4096;                                            \
    GLOAD_LDS(s, d);                                                         \
    GLOAD_LDS(s + 1024, d + 1024);                                           \
    GLOAD_LDS(s + 2048, d + 2048);                                           \
    GLOAD_LDS(s + 3072, d + 3072);                                           \
  }

  // one 16-code step: wait ring slot RB, consume, prefetch C+2 into PB
#define VQ_STEP(C, RB, PB, WAITIMM)                                          \
  {                                                                          \
    __builtin_amdgcn_s_waitcnt(WAITIMM);                                     \
    const char* tb = mybuf + (RB) * 4096;                                    \
    bf16x8 bh0 = *(const bf16x8*)(tb + 0    + (lane << 4));                  \
    bf16x8 bh1 = *(const bf16x8*)(tb + 1024 + (lane << 4));                  \
    bf16x8 bl0 = *(const bf16x8*)(tb + 2048 + (lane << 4));                  \
    bf16x8 bl1 = *(const bf16x8*)(tb + 3072 + (lane << 4));                  \
    float k2c = k2f[(C) * 16 + lcol];                                        \
    VQ_ISSUE((C) + 2, PB)                                                    \
    f32x4 p0 = {0.f, 0.f, 0.f, 0.f};                                         \
    f32x4 q0 = {0.f, 0.f, 0.f, 0.f};                                         \
    f32x4 p1 = {0.f, 0.f, 0.f, 0.f};                                         \
    f32x4 q1 = {0.f, 0.f, 0.f, 0.f};                                         \
    p0 = __builtin_amdgcn_mfma_f32_16x16x32_bf16(a0h0, bh0, p0, 0, 0, 0);    \
    q0 = __builtin_amdgcn_mfma_f32_16x16x32_bf16(a0h1, bh1, q0, 0, 0, 0);    \
    p1 = __builtin_amdgcn_mfma_f32_16x16x32_bf16(a1h0, bh0, p1, 0, 0, 0);    \
    q1 = __builtin_amdgcn_mfma_f32_16x16x32_bf16(a1h1, bh1, q1, 0, 0, 0);    \
    p0 = __builtin_amdgcn_mfma_f32_16x16x32_bf16(a0h0, bl0, p0, 0, 0, 0);    \
    q0 = __builtin_amdgcn_mfma_f32_16x16x32_bf16(a0h1, bl1, q0, 0, 0, 0);    \
    p1 = __builtin_amdgcn_mfma_f32_16x16x32_bf16(a1h0, bl0, p1, 0, 0, 0);    \
    q1 = __builtin_amdgcn_mfma_f32_16x16x32_bf16(a1h1, bl1, q1, 0, 0, 0);    \
    p0 = __builtin_amdgcn_mfma_f32_16x16x32_bf16(a0l0, bh0, p0, 0, 0, 0);    \
    q0 = __builtin_amdgcn_mfma_f32_16x16x32_bf16(a0l1, bh1, q0, 0, 0, 0);    \
    p1 = __builtin_amdgcn_mfma_f32_16x16x32_bf16(a1l0, bh0, p1, 0, 0, 0);    \
    q1 = __builtin_amdgcn_mfma_f32_16x16x32_bf16(a1l1, bh1, q1, 0, 0, 0);    \
    const int code = (C) * 16 + lcol;                                        \
    _Pragma("unroll")                                                        \
    for (int i = 0; i < 4; ++i) {                                            \
      float d0 = fmaf(-2.f, p0[i] + q0[i], k2c);                             \
      float nb2a = fminf(b2[i], fmaxf(bd[i], d0));                           \
      bool lt0 = d0 < bd[i];                                                 \
      bd[i] = lt0 ? d0 : bd[i];                                              \
      bi[i] = lt0 ? code : bi[i];                                            \
      b2[i] = nb2a;                                                          \
      float d1 = fmaf(-2.f, p1[i] + q1[i], k2c);                             \
      float nb2b = fminf(b2[4 + i], fmaxf(bd[4 + i], d1));                   \
      bool lt1 = d1 < bd[4 + i];                                             \
      bd[4 + i] = lt1 ? d1 : bd[4 + i];                                      \
      bi[4 + i] = lt1 ? code : bi[4 + i];                                    \
      b2[4 + i] = nb2b;                                                      \
    }                                                                        \
  }

  VQ_ISSUE(0, 0)
  VQ_ISSUE(1, 1)
  for (int c = 0; c < 126; c += 3) {
    VQ_STEP(c,     0, 2, WAIT_VM4)
    VQ_STEP(c + 1, 1, 0, WAIT_VM4)
    VQ_STEP(c + 2, 2, 1, WAIT_VM4)
  }
  VQ_STEP(126, 0, 2, WAIT_VM4)
  VQ_STEP(127, 1, 0, WAIT_VM0)
#undef VQ_STEP
#undef VQ_ISSUE

  // ---- reduce across the 16 col-classes ----
#pragma unroll
  for (int m = 1; m < 16; m <<= 1) {
#pragma unroll
    for (int i = 0; i < 8; ++i) {
      float od  = __shfl_xor(bd[i], m, 64);
      float od2 = __shfl_xor(b2[i], m, 64);
      int   oi  = __shfl_xor(bi[i], m, 64);
      float nb2 = fminf(fminf(b2[i], od2), fmaxf(bd[i], od));
      bool take = (od < bd[i]) || (od == bd[i] && oi < bi[i]);
      bd[i] = take ? od : bd[i];
      bi[i] = take ? oi : bi[i];
      b2[i] = nb2;
    }
  }

  float fit_p = 0.f;
  if (lcol == 0) {
#pragma unroll
    for (int i = 0; i < 8; ++i) {
      int s = i >> 2, ii = i & 3;
      int rloc = wave * 32 + s * 16 + quad * 4 + ii;
      int rowg = row0 + rloc;
      out[XL_OFF + rowg] = (float)bi[i];
      sIdx[rloc] = bi[i];
      fit_p += bd[i] + sx2[rloc];
      if (b2[i] - bd[i] < TAU) {
        int slot = atomicAdd(sFlagCnt, 1);   // LDS atomic (cheap)
        sFlagList[slot] = rowg;
      }
    }
  }
  __syncthreads();

  // one global atomic per block for the flag range
  int nloc = *sFlagCnt;
  if (tid == 0 && nloc > 0) *sFlagBase = atomicAdd(flag_cnt, nloc);
  __syncthreads();
  if (tid < nloc) {
    int gs = *sFlagBase + tid;
    if (gs < MAXFLAG) flags[gs] = sFlagList[tid];
  }

  // ---- gather chosen code rows (fp32) into LDS ----
  {
    int rr = tid >> 1, half = tid & 1;
    const float4* kr4 = (const float4*)(kg + (size_t)sIdx[rr] * WDIM + half * 32);
    float4* dst = (float4*)&kd[rr * 68 + half * 32];
#pragma unroll
    for (int j = 0; j < 8; ++j) dst[j] = kr4[j];
  }
  __syncthreads();

  // ---- x_d transposed write + commit ----
  float commit_p = 0.f;
  float* xdb = out + XD_OFF + (size_t)n * WDIM * TDIM + t0 + r;
#pragma unroll 8
  for (int i = 0; i < 32; ++i) {
    int w = 2 * i + wh;
    float xvv = xb[(size_t)w * TDIM];
    float kvv = kd[r * 68 + w];
    float df = kvv - xvv;
    commit_p = fmaf(df, df, commit_p);
    xdb[(size_t)w * TDIM] = kvv;
  }

  // ---- block scalar partials -> per-block arrays (no atomics) ----
  float v0 = sxp, v1 = x2p, v2 = commit_p, v3 = fit_p;
#pragma unroll
  for (int off = 32; off > 0; off >>= 1) {
    v0 += __shfl_down(v0, off, 64);
    v1 += __shfl_down(v1, off, 64);
    v2 += __shfl_down(v2, off, 64);
    v3 += __shfl_down(v3, off, 64);
  }
  if (lane == 0) {
    sPair[wave * 4 + 0] = v0;
    sPair[wave * 4 + 1] = v1;
    sPair[wave * 4 + 2] = v2;
    sPair[wave * 4 + 3] = v3;
  }
  __syncthreads();
  if (tid == 0) {
    part[0 * NBLK + blk] = sPair[0] + sPair[4];
    part[1 * NBLK + blk] = sPair[1] + sPair[5];
    part[2 * NBLK + blk] = sPair[2] + sPair[6];
    part[3 * NBLK + blk] = sPair[3] + sPair[7];
  }
}

// recheck pass 1: persistent grid; item = (flagged row, 256-code segment).
__launch_bounds__(256, 4)
__global__ void recheck_scan(const float* __restrict__ x,
                             const float* __restrict__ kg,
                             const float* __restrict__ k2g,
                             const int* __restrict__ flag_cnt,
                             const int* __restrict__ flags,
                             u64* __restrict__ slots) {
  __shared__ float sx[WDIM];
  __shared__ float sx2s;
  const int tid = threadIdx.x;
  int nf = *flag_cnt;
  if (nf > MAXFLAG) nf = MAXFLAG;
  const int total = nf * 8;

  for (int g = blockIdx.x; g < total; g += 2048) {
    const int fi  = g >> 3;
    const int seg = g & 7;
    const int row = flags[fi];
    const int n = row >> 13;
    const int t = row & (TDIM - 1);
    if (tid < WDIM) sx[tid] = x[(size_t)n * WDIM * TDIM + (size_t)tid * TDIM + t];
    __syncthreads();
    if (tid == 0) {   // np-pairwise x2
      float r8[8];
#pragma unroll
      for (int l = 0; l < 8; ++l) r8[l] = __fmul_rn(sx[l], sx[l]);
      for (int i = 8; i < WDIM; i += 8) {
#pragma unroll
        for (int l = 0; l < 8; ++l)
          r8[l] = __fadd_rn(r8[l], __fmul_rn(sx[i + l], sx[i + l]));
      }
      sx2s = __fadd_rn(__fadd_rn(__fadd_rn(r8[0], r8[1]), __fadd_rn(r8[2], r8[3])),
                       __fadd_rn(__fadd_rn(r8[4], r8[5]), __fadd_rn(r8[6], r8[7])));
    }
    __syncthreads();

    const int j = seg * 256 + tid;
    const float* kr = kg + (size_t)j * WDIM;
    float c = 0.f;
#pragma unroll
    for (int w = 0; w < WDIM; ++w)
      c = __fmaf_rn(sx[w], kr[w], c);
    float d = __fadd_rn(__fsub_rn(sx2s, __fmul_rn(2.0f, c)), k2g[j]);

    u64 key = ((u64)__float_as_uint(d) << 32) | (unsigned int)j;
#pragma unroll
    for (int off = 32; off > 0; off >>= 1) {
      u64 o = __shfl_down((unsigned long long)key, off, 64);
      if (o < key) key = o;
    }
    if ((tid & 63) == 0) atomicMin(&slots[fi], key);
    __syncthreads();
  }
}

// recheck pass 2: persistent write-back.
__global__ void recheck_write(const float* __restrict__ kg,
                              const int* __restrict__ flag_cnt,
                              const int* __restrict__ flags,
                              const u64* __restrict__ slots,
                              float* __restrict__ out) {
  int nf = *flag_cnt;
  if (nf > MAXFLAG) nf = MAXFLAG;
  const int w = threadIdx.x;
  for (int fi = blockIdx.x; fi < nf; fi += 256) {
    const int row = flags[fi];
    const int n = row >> 13;
    const int t = row & (TDIM - 1);
    const int j = (int)(slots[fi] & 0xFFFFFFFFULL);
    if (w == 0) out[XL_OFF + row] = (float)j;
    out[XD_OFF + (size_t)n * WDIM * TDIM + (size_t)w * TDIM + t] = kg[(size_t)j * WDIM + w];
  }
}

// finalize: sum per-block partials (fp64) + emit the 3 scalars.
__global__ void finalize_kernel(const float* __restrict__ part, float* __restrict__ out) {
  __shared__ double sred[4][64];
  const int tid = threadIdx.x;     // 256
  const int lane = tid & 63;
  const int wv = tid >> 6;
  double a[4] = {0.0, 0.0, 0.0, 0.0};
  for (int i = tid; i < NBLK; i += 256) {
#pragma unroll
    for (int q = 0; q < 4; ++q) a[q] += (double)part[q * NBLK + i];
  }
#pragma unroll
  for (int off = 32; off > 0; off >>= 1) {
#pragma unroll
    for (int q = 0; q < 4; ++q)
      a[q] += __shfl_down(a[q], off, 64);
  }
  if (lane == 0) {
#pragma unroll
    for (int q = 0; q < 4; ++q) sred[q][wv] = a[q];
  }
  __syncthreads();
  if (tid == 0) {
    double s0 = 0, s1 = 0, s2 = 0, s3 = 0;
#pragma unroll
    for (int wv2 = 0; wv2 < 4; ++wv2) {
      s0 += sred[0][wv2]; s1 += sred[1][wv2];
      s2 += sred[2][wv2]; s3 += sred[3][wv2];
    }
    double size = (double)XSIZE;
    double commit = s2 / size;
    double fit = s3 / (double)NROWS;
    double mean = s0 / size;
    double var = s1 / size - mean * mean;
    if (var < 0.0) var = 0.0;
    out[SCAL_OFF + 0] = (float)commit;
    out[SCAL_OFF + 1] = (float)fit;
    out[SCAL_OFF + 2] = (float)sqrt(var);
  }
}

extern "C" void kernel_launch(void* const* d_in, const int* in_sizes, int n_in,
                              void* d_out, int out_size, void* d_ws, size_t ws_size,
                              hipStream_t stream) {
  const float* x = (const float*)d_in[0];
  const float* kg = (const float*)d_in[1];
  float* out = (float*)d_out;
  float* k2   = (float*)((char*)d_ws + WS_K2_OFF);
  int* cnt    = (int*)((char*)d_ws + WS_CNT_OFF);
  int* flags  = (int*)((char*)d_ws + WS_FLAG_OFF);
  u64* slots  = (u64*)((char*)d_ws + WS_SLOT_OFF);
  float* part = (float*)((char*)d_ws + WS_PART_OFF);
  char* kfrag = (char*)d_ws + WS_KF_OFF;

  hipLaunchKernelGGL(prep_kernel, dim3(KBINS / 16), dim3(256), 0, stream,
                     kg, k2, kfrag, cnt, slots);
  hipLaunchKernelGGL(vq_mfma, dim3(NBLK), dim3(128), 0, stream,
                     x, kg, k2, kfrag, out, part, cnt, flags);
  hipLaunchKernelGGL(recheck_scan, dim3(2048), dim3(256), 0, stream,
                     x, kg, k2, cnt, flags, slots);
  hipLaunchKernelGGL(recheck_write, dim3(256), dim3(WDIM), 0, stream,
                     kg, cnt, flags, slots, out);
  hipLaunchKernelGGL(finalize_kernel, dim3(1), dim3(256), 0, stream, part, out);
}